// Round 8
// baseline (431220.459 us; speedup 1.0000x reference)
//
#include <hip/hip_runtime.h>
#include <stdint.h>

// VanillaRNN — Round 8: streamed-W replica with 4-deep rolling register window.
//
// Golden universe (decoded R4-R6): pure f32;
//   xh = chain_{k=0..127} fmaf(x[k], W_xh[k][j]); xh += b_h[j]
//   m  = chain_{i=0..511} fmaf(h[i], W_hh[i][j])   (single ascending chain)
//   h' = eigen_tanhf_fma(xh + m)                    (XLA/Eigen rational, FMA)
// Chain order is frozen (chaos, per-step gain ~3.3).
//
// R7 post-mortem: 208 resident floats/lane spilled (VGPR cap 128; 274 GB
// scratch writes). R8: NO persistent W registers. The 640-row sweep
// (8 W_xh blocks + 32 W_hh blocks, 16 rows each) streams through a 4-block
// rolling window pw[4][16] (64 regs): consume block n while loads for block
// n+4 are in flight (~512 cyc slack vs ~200-300 cyc L2 latency).
// Batch-interleaved LDS (h[i][b] pairs): one ds_read_b128 = 2 rows x 2
// batches -> 160 broadcast reads/lane/step. 1 barrier/step (double-buffer).
// 128 wgs x 512 threads, BT=2; __launch_bounds__(512) only (no 2nd arg —
// R7 evidence: 2nd arg acts as blocks/CU and halved the VGPR budget).

#define BATCH   256
#define SEQ     1024
#define IN_DIM  128
#define HIDDEN  512
#define CLASSES 128
#define NWG     (BATCH / 2)   // 128
#define NBX     (IN_DIM / 16)             // 8 stream blocks from W_xh
#define NBLK    (NBX + HIDDEN / 16)       // 40 total blocks of 16 rows

// ---- Eigen/XLA rational tanh f32, FMA variant — verbatim R5 ----
__device__ __forceinline__ float eigen_tanhf_fma(float ax) {
#pragma clang fp contract(off)
    const float pc = 7.99881172180175781f, mc = -7.99881172180175781f;
    float x = fmaxf(fminf(ax, pc), mc);
    float x2 = x * x;
    float p = __builtin_fmaf(x2, -2.76076847742355e-16f, 2.00018790482477e-13f);
    p = __builtin_fmaf(x2, p, -8.60467152213735e-11f);
    p = __builtin_fmaf(x2, p, 5.12229709037114e-08f);
    p = __builtin_fmaf(x2, p, 1.48572235717979e-05f);
    p = __builtin_fmaf(x2, p, 6.37261928875436e-04f);
    p = __builtin_fmaf(x2, p, 4.89352455891786e-03f);
    p = x * p;
    float q = __builtin_fmaf(x2, 1.19825839466702e-06f, 1.18534705686654e-04f);
    q = __builtin_fmaf(x2, q, 2.26843463243900e-03f);
    q = __builtin_fmaf(x2, q, 4.89352518554385e-03f);
    float r = p / q;
    return (fabsf(ax) < 0.0004f) ? ax : r;
}

__global__ __launch_bounds__(HIDDEN)
void rnn_stream(const float* __restrict__ x,
                const float* __restrict__ W_hh,
                const float* __restrict__ W_xh,
                const float* __restrict__ W_hy,
                const float* __restrict__ b_h,
                const float* __restrict__ b_y,
                float* __restrict__ out)
{
    // batch-interleaved double-buffered state: [buf][row][batch]
    __shared__ alignas(16) float hti[2][HIDDEN][2];
    __shared__ alignas(16) float xti[2][IN_DIM][2];

    const int j = threadIdx.x;   // hidden column
    const int g = blockIdx.x;

    const float bh = b_h[j];
    const float* pX = W_xh + j;  // lane's column in W_xh
    const float* pH = W_hh + j;  // lane's column in W_hh

    const float* xb0 = x + (size_t)(2 * g) * SEQ * IN_DIM;
    const float* xb1 = xb0 + (size_t)SEQ * IN_DIM;

    // init h=0, stage x(t=0) into buf 0
    hti[0][j][0] = 0.0f;
    hti[0][j][1] = 0.0f;
    if (j < 2 * IN_DIM) {
        const int b = j >> 7, k = j & (IN_DIM - 1);
        xti[0][k][b] = (b ? xb1 : xb0)[k];
    }
    __syncthreads();

    for (int t = 0; t < SEQ; ++t) {
        const int cur = t & 1, nxt = cur ^ 1;
        float a0, a1, m0, m1;
        {
#pragma clang fp contract(off)
            float pw[4][16];

            // prologue: blocks 0..3 in flight
            #pragma unroll
            for (int n = 0; n < 4; ++n) {
                const float* base = (n < NBX) ? (pX + (size_t)(16 * n) * HIDDEN)
                                              : (pH + (size_t)(16 * (n - NBX)) * HIDDEN);
                #pragma unroll
                for (int r = 0; r < 16; ++r)
                    pw[n][r] = base[(size_t)r * HIDDEN];
            }

            a0 = 0.0f; a1 = 0.0f; m0 = 0.0f; m1 = 0.0f;

            #pragma unroll
            for (int n = 0; n < NBLK; ++n) {
                const int w = n & 3;
                if (n < NBX) {
                    // xh chain rows 16n..16n+15 (x operands, batch-interleaved)
                    #pragma unroll
                    for (int r2 = 0; r2 < 8; ++r2) {
                        const int row = 16 * n + 2 * r2;
                        const float4 xv = *(const float4*)&xti[cur][row][0];
                        a0 = __builtin_fmaf(xv.x, pw[w][2 * r2 + 0], a0);
                        a1 = __builtin_fmaf(xv.y, pw[w][2 * r2 + 0], a1);
                        a0 = __builtin_fmaf(xv.z, pw[w][2 * r2 + 1], a0);
                        a1 = __builtin_fmaf(xv.w, pw[w][2 * r2 + 1], a1);
                    }
                    if (n == NBX - 1) {   // end of xh chain: += b_h
                        a0 = a0 + bh;
                        a1 = a1 + bh;
                    }
                } else {
                    // hh chain rows 16(n-8)..+15 (h operands)
                    #pragma unroll
                    for (int r2 = 0; r2 < 8; ++r2) {
                        const int row = 16 * (n - NBX) + 2 * r2;
                        const float4 hv = *(const float4*)&hti[cur][row][0];
                        m0 = __builtin_fmaf(hv.x, pw[w][2 * r2 + 0], m0);
                        m1 = __builtin_fmaf(hv.y, pw[w][2 * r2 + 0], m1);
                        m0 = __builtin_fmaf(hv.z, pw[w][2 * r2 + 1], m0);
                        m1 = __builtin_fmaf(hv.w, pw[w][2 * r2 + 1], m1);
                    }
                }
                // prefetch block n+4 into the slot just freed
                if (n + 4 < NBLK) {
                    const int np = n + 4;
                    const float* base = (np < NBX) ? (pX + (size_t)(16 * np) * HIDDEN)
                                                   : (pH + (size_t)(16 * (np - NBX)) * HIDDEN);
                    #pragma unroll
                    for (int r = 0; r < 16; ++r)
                        pw[w][r] = base[(size_t)r * HIDDEN];
                }
            }
        }

        const float h0 = eigen_tanhf_fma(a0 + m0);
        const float h1 = eigen_tanhf_fma(a1 + m1);

        // stage x for t+1 into nxt buffer
        if (t + 1 < SEQ && j < 2 * IN_DIM) {
            const int b = j >> 7, k = j & (IN_DIM - 1);
            xti[nxt][k][b] = (b ? xb1 : xb0)[(t + 1) * IN_DIM + k];
        }
        *(float2*)&hti[nxt][j][0] = make_float2(h0, h1);
        __syncthreads();
    }

    // ---- head: out[2g+b, c] = h_final[b,:] @ W_hy[:,c] + b_y[c] ----
    // final h in buffer 0 (SEQ even); f64 acc, same order as R5/R6.
    if (j < 2 * CLASSES) {
        const int b = j >> 7;
        const int c = j & (CLASSES - 1);
        double acc = 0.0;
        for (int i = 0; i < HIDDEN; ++i) {
            acc += (double)hti[0][i][b] * (double)W_hy[i * CLASSES + c];
        }
        acc += (double)b_y[c];
        out[(size_t)(2 * g + b) * CLASSES + c] = (float)acc;
    }
}

extern "C" void kernel_launch(void* const* d_in, const int* in_sizes, int n_in,
                              void* d_out, int out_size, void* d_ws, size_t ws_size,
                              hipStream_t stream)
{
    const float *x, *W_hh, *W_xh, *W_hy, *b_h, *b_y;
    if (in_sizes[0] == BATCH * SEQ * IN_DIM) {
        x    = (const float*)d_in[0];
        W_hh = (const float*)d_in[1];
        W_xh = (const float*)d_in[2];
        W_hy = (const float*)d_in[3];
        b_h  = (const float*)d_in[4];
        b_y  = (const float*)d_in[5];
    } else {
        W_hh = (const float*)d_in[0];
        W_hy = (const float*)d_in[1];
        W_xh = (const float*)d_in[2];
        b_h  = (const float*)d_in[3];
        b_y  = (const float*)d_in[4];
        x    = (const float*)d_in[5];
    }
    float* out = (float*)d_out;
    (void)n_in; (void)out_size; (void)d_ws; (void)ws_size;

    rnn_stream<<<NWG, HIDDEN, 0, stream>>>(x, W_hh, W_xh, W_hy, b_h, b_y, out);
}

// Round 9
// 53376.050 us; speedup vs baseline: 8.0789x; 8.0789x over previous
//
#include <hip/hip_runtime.h>
#include <stdint.h>

// VanillaRNN — Round 9: spill-free direct-load replica (L2-BW-bound design).
//
// Golden universe (decoded R4-R6): pure f32;
//   xh = chain_{k=0..127} fmaf(x[k], W_xh[k][j]); xh += b_h[j]
//   m  = chain_{i=0..511} fmaf(h[i], W_hh[i][j])   (single ascending chain)
//   h' = eigen_tanhf_fma(xh + m)                    (XLA/Eigen rational, FMA)
// Chain order frozen (chaos, per-step gain ~3.3).
//
// R7/R8 post-mortem: any large per-lane register array spills at this block
// size (VGPR target ~128) -> 270+ GB scratch traffic, 400+ ms. R9 uses NO
// per-lane arrays: W is loaded directly (coalesced, lane j = column j) in
// 16-row groups — 16 independent loads then 32 chained FMAs, a ~16-reg
// software pipeline the compiler can schedule without spilling.
//
// Cost model: per XCD = 16 blocks x 1.31 MB/step from L2 = 21 MB / 1800 B/cyc
// = 4.9 us/step -> ~5 ms floor; VALU 2560 cyc/SIMD/step = 2.1 us. L2-bound.
// R6 evidence: without spill traffic W stays L2/L3-resident (FETCH was 94 MB).
//
// State: batch-interleaved h/x in LDS, double-buffered, broadcast float4
// reads, 1 barrier/step. BT=2, 128 wgs x 512 threads.

#define BATCH   256
#define SEQ     1024
#define IN_DIM  128
#define HIDDEN  512
#define CLASSES 128
#define NWG     (BATCH / 2)   // 128

// ---- Eigen/XLA rational tanh f32, FMA variant — verbatim R5 ----
__device__ __forceinline__ float eigen_tanhf_fma(float ax) {
#pragma clang fp contract(off)
    const float pc = 7.99881172180175781f, mc = -7.99881172180175781f;
    float x = fmaxf(fminf(ax, pc), mc);
    float x2 = x * x;
    float p = __builtin_fmaf(x2, -2.76076847742355e-16f, 2.00018790482477e-13f);
    p = __builtin_fmaf(x2, p, -8.60467152213735e-11f);
    p = __builtin_fmaf(x2, p, 5.12229709037114e-08f);
    p = __builtin_fmaf(x2, p, 1.48572235717979e-05f);
    p = __builtin_fmaf(x2, p, 6.37261928875436e-04f);
    p = __builtin_fmaf(x2, p, 4.89352455891786e-03f);
    p = x * p;
    float q = __builtin_fmaf(x2, 1.19825839466702e-06f, 1.18534705686654e-04f);
    q = __builtin_fmaf(x2, q, 2.26843463243900e-03f);
    q = __builtin_fmaf(x2, q, 4.89352518554385e-03f);
    float r = p / q;
    return (fabsf(ax) < 0.0004f) ? ax : r;
}

__global__ __launch_bounds__(HIDDEN)
void rnn_fast(const float* __restrict__ x,
              const float* __restrict__ W_hh,
              const float* __restrict__ W_xh,
              const float* __restrict__ W_hy,
              const float* __restrict__ b_h,
              const float* __restrict__ b_y,
              float* __restrict__ out)
{
    // batch-interleaved double-buffered state: [buf][row][batch]
    __shared__ alignas(16) float hti[2][HIDDEN][2];   // 8 KB
    __shared__ alignas(16) float xti[2][IN_DIM][2];   // 2 KB

    const int j = threadIdx.x;   // hidden column
    const int g = blockIdx.x;

    const float bh = b_h[j];
    const float* __restrict__ pX = W_xh + j;  // lane's column in W_xh
    const float* __restrict__ pH = W_hh + j;  // lane's column in W_hh

    const float* xb0 = x + (size_t)(2 * g) * SEQ * IN_DIM;
    const float* xb1 = xb0 + (size_t)SEQ * IN_DIM;

    hti[0][j][0] = 0.0f;
    hti[0][j][1] = 0.0f;
    if (j < 2 * IN_DIM) {
        const int b = j >> 7, k = j & (IN_DIM - 1);
        xti[0][k][b] = (b ? xb1 : xb0)[k];
    }
    __syncthreads();

    for (int t = 0; t < SEQ; ++t) {
        const int cur = t & 1, nxt = cur ^ 1;
        float a0, a1, m0, m1;
        {
#pragma clang fp contract(off)
            // ---- xh chain: 8 groups of 16 rows ----
            a0 = 0.0f; a1 = 0.0f;
            for (int i0 = 0; i0 < IN_DIM; i0 += 16) {
                float w00 = pX[(size_t)(i0 +  0) * HIDDEN];
                float w01 = pX[(size_t)(i0 +  1) * HIDDEN];
                float w02 = pX[(size_t)(i0 +  2) * HIDDEN];
                float w03 = pX[(size_t)(i0 +  3) * HIDDEN];
                float w04 = pX[(size_t)(i0 +  4) * HIDDEN];
                float w05 = pX[(size_t)(i0 +  5) * HIDDEN];
                float w06 = pX[(size_t)(i0 +  6) * HIDDEN];
                float w07 = pX[(size_t)(i0 +  7) * HIDDEN];
                float w08 = pX[(size_t)(i0 +  8) * HIDDEN];
                float w09 = pX[(size_t)(i0 +  9) * HIDDEN];
                float w10 = pX[(size_t)(i0 + 10) * HIDDEN];
                float w11 = pX[(size_t)(i0 + 11) * HIDDEN];
                float w12 = pX[(size_t)(i0 + 12) * HIDDEN];
                float w13 = pX[(size_t)(i0 + 13) * HIDDEN];
                float w14 = pX[(size_t)(i0 + 14) * HIDDEN];
                float w15 = pX[(size_t)(i0 + 15) * HIDDEN];
                const float4 v0 = *(const float4*)&xti[cur][i0 +  0][0];
                const float4 v1 = *(const float4*)&xti[cur][i0 +  2][0];
                const float4 v2 = *(const float4*)&xti[cur][i0 +  4][0];
                const float4 v3 = *(const float4*)&xti[cur][i0 +  6][0];
                const float4 v4 = *(const float4*)&xti[cur][i0 +  8][0];
                const float4 v5 = *(const float4*)&xti[cur][i0 + 10][0];
                const float4 v6 = *(const float4*)&xti[cur][i0 + 12][0];
                const float4 v7 = *(const float4*)&xti[cur][i0 + 14][0];
                a0 = __builtin_fmaf(v0.x, w00, a0); a1 = __builtin_fmaf(v0.y, w00, a1);
                a0 = __builtin_fmaf(v0.z, w01, a0); a1 = __builtin_fmaf(v0.w, w01, a1);
                a0 = __builtin_fmaf(v1.x, w02, a0); a1 = __builtin_fmaf(v1.y, w02, a1);
                a0 = __builtin_fmaf(v1.z, w03, a0); a1 = __builtin_fmaf(v1.w, w03, a1);
                a0 = __builtin_fmaf(v2.x, w04, a0); a1 = __builtin_fmaf(v2.y, w04, a1);
                a0 = __builtin_fmaf(v2.z, w05, a0); a1 = __builtin_fmaf(v2.w, w05, a1);
                a0 = __builtin_fmaf(v3.x, w06, a0); a1 = __builtin_fmaf(v3.y, w06, a1);
                a0 = __builtin_fmaf(v3.z, w07, a0); a1 = __builtin_fmaf(v3.w, w07, a1);
                a0 = __builtin_fmaf(v4.x, w08, a0); a1 = __builtin_fmaf(v4.y, w08, a1);
                a0 = __builtin_fmaf(v4.z, w09, a0); a1 = __builtin_fmaf(v4.w, w09, a1);
                a0 = __builtin_fmaf(v5.x, w10, a0); a1 = __builtin_fmaf(v5.y, w10, a1);
                a0 = __builtin_fmaf(v5.z, w11, a0); a1 = __builtin_fmaf(v5.w, w11, a1);
                a0 = __builtin_fmaf(v6.x, w12, a0); a1 = __builtin_fmaf(v6.y, w12, a1);
                a0 = __builtin_fmaf(v6.z, w13, a0); a1 = __builtin_fmaf(v6.w, w13, a1);
                a0 = __builtin_fmaf(v7.x, w14, a0); a1 = __builtin_fmaf(v7.y, w14, a1);
                a0 = __builtin_fmaf(v7.z, w15, a0); a1 = __builtin_fmaf(v7.w, w15, a1);
            }
            a0 = a0 + bh;
            a1 = a1 + bh;

            // ---- hh chain: 32 groups of 16 rows ----
            m0 = 0.0f; m1 = 0.0f;
            for (int i0 = 0; i0 < HIDDEN; i0 += 16) {
                float w00 = pH[(size_t)(i0 +  0) * HIDDEN];
                float w01 = pH[(size_t)(i0 +  1) * HIDDEN];
                float w02 = pH[(size_t)(i0 +  2) * HIDDEN];
                float w03 = pH[(size_t)(i0 +  3) * HIDDEN];
                float w04 = pH[(size_t)(i0 +  4) * HIDDEN];
                float w05 = pH[(size_t)(i0 +  5) * HIDDEN];
                float w06 = pH[(size_t)(i0 +  6) * HIDDEN];
                float w07 = pH[(size_t)(i0 +  7) * HIDDEN];
                float w08 = pH[(size_t)(i0 +  8) * HIDDEN];
                float w09 = pH[(size_t)(i0 +  9) * HIDDEN];
                float w10 = pH[(size_t)(i0 + 10) * HIDDEN];
                float w11 = pH[(size_t)(i0 + 11) * HIDDEN];
                float w12 = pH[(size_t)(i0 + 12) * HIDDEN];
                float w13 = pH[(size_t)(i0 + 13) * HIDDEN];
                float w14 = pH[(size_t)(i0 + 15) * HIDDEN - HIDDEN]; // i0+14
                float w15 = pH[(size_t)(i0 + 15) * HIDDEN];
                const float4 v0 = *(const float4*)&hti[cur][i0 +  0][0];
                const float4 v1 = *(const float4*)&hti[cur][i0 +  2][0];
                const float4 v2 = *(const float4*)&hti[cur][i0 +  4][0];
                const float4 v3 = *(const float4*)&hti[cur][i0 +  6][0];
                const float4 v4 = *(const float4*)&hti[cur][i0 +  8][0];
                const float4 v5 = *(const float4*)&hti[cur][i0 + 10][0];
                const float4 v6 = *(const float4*)&hti[cur][i0 + 12][0];
                const float4 v7 = *(const float4*)&hti[cur][i0 + 14][0];
                m0 = __builtin_fmaf(v0.x, w00, m0); m1 = __builtin_fmaf(v0.y, w00, m1);
                m0 = __builtin_fmaf(v0.z, w01, m0); m1 = __builtin_fmaf(v0.w, w01, m1);
                m0 = __builtin_fmaf(v1.x, w02, m0); m1 = __builtin_fmaf(v1.y, w02, m1);
                m0 = __builtin_fmaf(v1.z, w03, m0); m1 = __builtin_fmaf(v1.w, w03, m1);
                m0 = __builtin_fmaf(v2.x, w04, m0); m1 = __builtin_fmaf(v2.y, w04, m1);
                m0 = __builtin_fmaf(v2.z, w05, m0); m1 = __builtin_fmaf(v2.w, w05, m1);
                m0 = __builtin_fmaf(v3.x, w06, m0); m1 = __builtin_fmaf(v3.y, w06, m1);
                m0 = __builtin_fmaf(v3.z, w07, m0); m1 = __builtin_fmaf(v3.w, w07, m1);
                m0 = __builtin_fmaf(v4.x, w08, m0); m1 = __builtin_fmaf(v4.y, w08, m1);
                m0 = __builtin_fmaf(v4.z, w09, m0); m1 = __builtin_fmaf(v4.w, w09, m1);
                m0 = __builtin_fmaf(v5.x, w10, m0); m1 = __builtin_fmaf(v5.y, w10, m1);
                m0 = __builtin_fmaf(v5.z, w11, m0); m1 = __builtin_fmaf(v5.w, w11, m1);
                m0 = __builtin_fmaf(v6.x, w12, m0); m1 = __builtin_fmaf(v6.y, w12, m1);
                m0 = __builtin_fmaf(v6.z, w13, m0); m1 = __builtin_fmaf(v6.w, w13, m1);
                m0 = __builtin_fmaf(v7.x, w14, m0); m1 = __builtin_fmaf(v7.y, w14, m1);
                m0 = __builtin_fmaf(v7.z, w15, m0); m1 = __builtin_fmaf(v7.w, w15, m1);
            }
        }

        const float h0 = eigen_tanhf_fma(a0 + m0);
        const float h1 = eigen_tanhf_fma(a1 + m1);

        if (t + 1 < SEQ && j < 2 * IN_DIM) {
            const int b = j >> 7, k = j & (IN_DIM - 1);
            xti[nxt][k][b] = (b ? xb1 : xb0)[(t + 1) * IN_DIM + k];
        }
        *(float2*)&hti[nxt][j][0] = make_float2(h0, h1);
        __syncthreads();
    }

    // ---- head: out[2g+b, c] = h_final[b,:] @ W_hy[:,c] + b_y[c] ----
    // final h in buffer 0 (SEQ even); f64 acc, same as R5-R8 (absmax 0.125).
    if (j < 2 * CLASSES) {
        const int b = j >> 7;
        const int c = j & (CLASSES - 1);
        double acc = 0.0;
        for (int i = 0; i < HIDDEN; ++i) {
            acc += (double)hti[0][i][b] * (double)W_hy[i * CLASSES + c];
        }
        acc += (double)b_y[c];
        out[(size_t)(2 * g + b) * CLASSES + c] = (float)acc;
    }
}

extern "C" void kernel_launch(void* const* d_in, const int* in_sizes, int n_in,
                              void* d_out, int out_size, void* d_ws, size_t ws_size,
                              hipStream_t stream)
{
    const float *x, *W_hh, *W_xh, *W_hy, *b_h, *b_y;
    if (in_sizes[0] == BATCH * SEQ * IN_DIM) {
        x    = (const float*)d_in[0];
        W_hh = (const float*)d_in[1];
        W_xh = (const float*)d_in[2];
        W_hy = (const float*)d_in[3];
        b_h  = (const float*)d_in[4];
        b_y  = (const float*)d_in[5];
    } else {
        W_hh = (const float*)d_in[0];
        W_hy = (const float*)d_in[1];
        W_xh = (const float*)d_in[2];
        b_h  = (const float*)d_in[3];
        b_y  = (const float*)d_in[4];
        x    = (const float*)d_in[5];
    }
    float* out = (float*)d_out;
    (void)n_in; (void)out_size; (void)d_ws; (void)ws_size;

    rnn_fast<<<NWG, HIDDEN, 0, stream>>>(x, W_hh, W_xh, W_hy, b_h, b_y, out);
}